// Round 5
// baseline (68.819 us; speedup 1.0000x reference)
//
#include <hip/hip_runtime.h>
#include <hip/hip_bf16.h>

#define B_   4
#define N_   8192
#define CIN_ 64
#define H_   8
#define HD_  512
#define EPS_ 1e-5f
#define NCH_ 32   // k1 chunks per (b,h); each block covers 256 rows

typedef __bf16 bf16x8 __attribute__((ext_vector_type(8)));
typedef __bf16 bf16x4 __attribute__((ext_vector_type(4)));
typedef float  f32x4  __attribute__((ext_vector_type(4)));

// ---------------- workspace layout ----------------
constexpr size_t OFF_MTH  = 0;
constexpr size_t SZ_MTP   = (size_t)B_ * 64 * HD_ * 2;            // 256 KB bf16 plane
constexpr size_t OFF_MTL  = OFF_MTH + SZ_MTP;
constexpr size_t OFF_KVG  = OFF_MTL + SZ_MTP;
constexpr size_t SZ_KVG   = (size_t)B_ * H_ * 4096 * 4;           // 512 KB fp32
constexpr size_t OFF_PART = OFF_KVG + SZ_KVG;
constexpr size_t SZ_PART  = (size_t)B_ * H_ * NCH_ * 4096 * 4;    // 16 MB fp32
constexpr size_t WS_NEED  = OFF_PART + SZ_PART;

// ---------------- helpers ----------------
// load 8 consecutive fp32 and convert to bf16x8 (replaces prep_cast)
__device__ __forceinline__ bf16x8 ld_cvt8(const float* __restrict__ p) {
  const f32x4 a = *reinterpret_cast<const f32x4*>(p);
  const f32x4 b = *reinterpret_cast<const f32x4*>(p + 4);
  bf16x8 o;
#pragma unroll
  for (int r = 0; r < 4; ++r) { o[r] = (__bf16)a[r]; o[4 + r] = (__bf16)b[r]; }
  return o;
}

// DPP 16-lane rotation reduce (VALU-only)
template <int CTRL>
__device__ __forceinline__ float dpp_radd(float x) {
  union { float f; int i; } u, v;
  u.f = x;
  v.i = __builtin_amdgcn_update_dpp(0, u.i, CTRL, 0xF, 0xF, false);
  return x + v.f;
}
__device__ __forceinline__ float red16(float x) {
  x = dpp_radd<0x121>(x);  // row_ror:1
  x = dpp_radd<0x122>(x);  // row_ror:2
  x = dpp_radd<0x124>(x);  // row_ror:4
  x = dpp_radd<0x128>(x);  // row_ror:8
  return x;
}

// ---------------- K1: per-(b,h,chunk) KV partial, 4 waves/block --------------
// Each wave: ONE 64-row tile. Block reduces 4 waves' KV -> 1 partial.
__global__ __launch_bounds__(256, 2) void k1_kv(
    const float* __restrict__ v, const float* __restrict__ wk,
    const float* __restrict__ wv, const float* __restrict__ kbias,
    const float* __restrict__ vbias, const float* __restrict__ lnkw,
    const float* __restrict__ lnkb, float* __restrict__ part) {
  const int ch = blockIdx.x, h = blockIdx.y, b = blockIdx.z;
  const int tid = threadIdx.x, w = tid >> 6, lane = tid & 63;
  const int l15 = lane & 15, g = lane >> 4;
  __shared__ alignas(16) char smem[73728];
  __bf16 (*Kt)[72] = reinterpret_cast<__bf16(*)[72]>(smem + w * 18432);          // [d][n]
  __bf16 (*Vt)[72] = reinterpret_cast<__bf16(*)[72]>(smem + w * 18432 + 9216);   // [e][n]

  const f32x4 z4 = {0.f, 0.f, 0.f, 0.f};
  f32x4 kv[4][4];
#pragma unroll
  for (int i = 0; i < 4; ++i)
#pragma unroll
    for (int j = 0; j < 4; ++j) kv[i][j] = z4;

  float kb[4], vbi[4], lw[4], lb[4];
#pragma unroll
  for (int c = 0; c < 4; ++c) {
    const int col = h * 64 + c * 16 + l15;
    kb[c] = kbias[col]; vbi[c] = vbias[col];
    lw[c] = lnkw[col];  lb[c] = lnkb[col];
  }
  // weight B-frags: fp32 rows -> bf16 (L2-hot, once per block lifetime)
  bf16x8 wkf[4][2], wvf[4][2];
#pragma unroll
  for (int c = 0; c < 4; ++c)
#pragma unroll
    for (int kk = 0; kk < 2; ++kk) {
      wkf[c][kk] = ld_cvt8(wk + (size_t)(h * 64 + c * 16 + l15) * CIN_ + kk * 32 + g * 8);
      wvf[c][kk] = ld_cvt8(wv + (size_t)(h * 64 + c * 16 + l15) * CIN_ + kk * 32 + g * 8);
    }

  const int row0 = ch * 256 + w * 64;
  bf16x8 av[4][2];
#pragma unroll
  for (int m = 0; m < 4; ++m)
#pragma unroll
    for (int kk = 0; kk < 2; ++kk)
      av[m][kk] = ld_cvt8(v + ((size_t)b * N_ + row0 + m * 16 + l15) * CIN_ + kk * 32 + g * 8);

  // ---- K proj + bias + LN -> Kt (m-pairs to cap VGPR) ----
#pragma unroll
  for (int mp = 0; mp < 2; ++mp) {
    f32x4 acc[2][4];
#pragma unroll
    for (int mi = 0; mi < 2; ++mi)
#pragma unroll
      for (int c = 0; c < 4; ++c) {
        f32x4 a = z4;
        a = __builtin_amdgcn_mfma_f32_16x16x32_bf16(av[mp * 2 + mi][0], wkf[c][0], a, 0, 0, 0);
        a = __builtin_amdgcn_mfma_f32_16x16x32_bf16(av[mp * 2 + mi][1], wkf[c][1], a, 0, 0, 0);
        acc[mi][c] = a;
      }
#pragma unroll
    for (int mi = 0; mi < 2; ++mi) {
      const int m = mp * 2 + mi;
      float s[4] = {0, 0, 0, 0}, ss[4] = {0, 0, 0, 0};
#pragma unroll
      for (int c = 0; c < 4; ++c)
#pragma unroll
        for (int r = 0; r < 4; ++r) {
          float x = acc[mi][c][r] + kb[c];
          acc[mi][c][r] = x;
          s[r] += x; ss[r] += x * x;
        }
#pragma unroll
      for (int r = 0; r < 4; ++r) {
        const float S = red16(s[r]), Q = red16(ss[r]);
        const float mu = S * (1.f / 64.f);
        const float var = Q * (1.f / 64.f) - mu * mu;
        const float rstd = rsqrtf(var + EPS_);
#pragma unroll
        for (int c = 0; c < 4; ++c)
          acc[mi][c][r] = (acc[mi][c][r] - mu) * rstd * lw[c] + lb[c];
      }
#pragma unroll
      for (int c = 0; c < 4; ++c) {
        bf16x4 p;
#pragma unroll
        for (int r = 0; r < 4; ++r) p[r] = (__bf16)acc[mi][c][r];
        *reinterpret_cast<bf16x4*>(&Kt[c * 16 + l15][m * 16 + g * 4]) = p;
      }
    }
  }
  // ---- V proj + bias -> Vt ----
#pragma unroll
  for (int mp = 0; mp < 2; ++mp) {
    f32x4 acc[2][4];
#pragma unroll
    for (int mi = 0; mi < 2; ++mi)
#pragma unroll
      for (int c = 0; c < 4; ++c) {
        f32x4 a = z4;
        a = __builtin_amdgcn_mfma_f32_16x16x32_bf16(av[mp * 2 + mi][0], wvf[c][0], a, 0, 0, 0);
        a = __builtin_amdgcn_mfma_f32_16x16x32_bf16(av[mp * 2 + mi][1], wvf[c][1], a, 0, 0, 0);
        acc[mi][c] = a;
      }
#pragma unroll
    for (int mi = 0; mi < 2; ++mi) {
      const int m = mp * 2 + mi;
#pragma unroll
      for (int c = 0; c < 4; ++c) {
        bf16x4 p;
#pragma unroll
        for (int r = 0; r < 4; ++r) p[r] = (__bf16)(acc[mi][c][r] + vbi[c]);
        *reinterpret_cast<bf16x4*>(&Vt[c * 16 + l15][m * 16 + g * 4]) = p;
      }
    }
  }

  __syncthreads();  // LDS writes -> reads: enforce order (R2 lesson)

  // ---- KV accumulate ----
  bf16x8 va[4][2];
#pragma unroll
  for (int et = 0; et < 4; ++et)
#pragma unroll
    for (int nk = 0; nk < 2; ++nk)
      va[et][nk] = *reinterpret_cast<const bf16x8*>(&Vt[et * 16 + l15][nk * 32 + g * 8]);
#pragma unroll
  for (int dt = 0; dt < 4; ++dt) {
    bf16x8 ka[2];
#pragma unroll
    for (int nk = 0; nk < 2; ++nk)
      ka[nk] = *reinterpret_cast<const bf16x8*>(&Kt[dt * 16 + l15][nk * 32 + g * 8]);
#pragma unroll
    for (int et = 0; et < 4; ++et) {
      kv[dt][et] = __builtin_amdgcn_mfma_f32_16x16x32_bf16(ka[0], va[et][0], kv[dt][et], 0, 0, 0);
      kv[dt][et] = __builtin_amdgcn_mfma_f32_16x16x32_bf16(ka[1], va[et][1], kv[dt][et], 0, 0, 0);
    }
  }

  __syncthreads();  // all reads done before red overwrites Kt/Vt

  // ---- in-block reduction: 4 waves' KV -> one partial (stored [e][d]) ----
  float* red = reinterpret_cast<float*>(smem + w * 17408);  // [64][68] padded
#pragma unroll
  for (int dt = 0; dt < 4; ++dt)
#pragma unroll
    for (int et = 0; et < 4; ++et)
      *reinterpret_cast<f32x4*>(red + (et * 16 + l15) * 68 + dt * 16 + g * 4) = kv[dt][et];
  __syncthreads();
  float* p0 = part + (size_t)((b * H_ + h) * NCH_ + ch) * 4096;
#pragma unroll
  for (int k = 0; k < 4; ++k) {
    const int idx4 = tid + k * 256;           // f32x4 index
    const int e = idx4 >> 4, d = (idx4 & 15) * 4;
    f32x4 sum = *reinterpret_cast<const f32x4*>(
        reinterpret_cast<const float*>(smem) + e * 68 + d);
#pragma unroll
    for (int ww = 1; ww < 4; ++ww)
      sum += *reinterpret_cast<const f32x4*>(
          reinterpret_cast<const float*>(smem + ww * 17408) + e * 68 + d);
    *reinterpret_cast<f32x4*>(p0 + idx4 * 4) = sum;
  }
}

// ---------------- K2a: parallel tree-reduce partials -> KVg ----------------
__global__ __launch_bounds__(256) void k2a_reduce(const float* __restrict__ part,
                                                 float* __restrict__ KVg) {
  const int s = blockIdx.x, h = blockIdx.y, b = blockIdx.z;  // s: 0..15
  const int idx = s * 256 + threadIdx.x;
  const float* p0 = part + (size_t)((b * H_ + h) * NCH_) * 4096 + idx;
  float acc = 0.f;
#pragma unroll 8
  for (int ch = 0; ch < NCH_; ++ch) acc += p0[(size_t)ch * 4096];
  KVg[(size_t)(b * H_ + h) * 4096 + idx] = acc;
}

// ---- K2b: Mt[b][E][h*64+d] = (KV @ ow_h^T)[d,E]/N, stored bf16 hi+lo -------
__global__ __launch_bounds__(256) void k2b_mt(const float* __restrict__ KVg,
                                              const float* __restrict__ ow,
                                              __bf16* __restrict__ MtH,
                                              __bf16* __restrict__ MtL) {
  const int z = blockIdx.x, h = blockIdx.y, b = blockIdx.z;  // z: 16-row E-slice
  const int tid = threadIdx.x;
  __shared__ float KVl[4096];      // [e][d]
  __shared__ float OWl[16][65];
  const float* kv0 = KVg + (size_t)(b * H_ + h) * 4096;
  for (int i = tid; i < 4096; i += 256) KVl[i] = kv0[i];
  for (int i = tid; i < 16 * 64; i += 256) {
    int E = i >> 6, c = i & 63;
    OWl[E][c] = ow[(size_t)(z * 16 + E) * HD_ + h * 64 + c];
  }
  __syncthreads();
  for (int i = tid; i < 1024; i += 256) {
    int E = i >> 6, d = i & 63;
    float s = 0.f;
#pragma unroll
    for (int c = 0; c < 64; ++c) s += KVl[c * 64 + d] * OWl[E][c];
    s *= (1.0f / N_);
    const size_t o = (size_t)(b * 64 + z * 16 + E) * HD_ + h * 64 + d;
    const __bf16 hi = (__bf16)s;
    MtH[o] = hi;
    MtL[o] = (__bf16)(s - (float)hi);
  }
}

// ---------------- K3: out^T tiles = Mt(hi+lo) @ Qt, Mt-frags in regs ---------
__global__ __launch_bounds__(256, 2) void k3_out(
    const float* __restrict__ v, const float* __restrict__ wq,
    const float* __restrict__ qbias, const float* __restrict__ lnqw,
    const float* __restrict__ lnqb, const __bf16* __restrict__ MtH,
    const __bf16* __restrict__ MtL, const float* __restrict__ obias,
    float* __restrict__ out) {
  const int nt = blockIdx.x, b = blockIdx.y;
  const int tid = threadIdx.x, w = tid >> 6, lane = tid & 63;
  const int l15 = lane & 15, g = lane >> 4;
  __shared__ __bf16 Qt[64][520];  // [n][j]
  const int row0 = nt * 64;
  const f32x4 z4 = {0.f, 0.f, 0.f, 0.f};

  // ---- phase 1: transposed Q-proj + LN -> Qt (wave w: heads 2w, 2w+1) ----
  bf16x8 bv[4][2];
#pragma unroll
  for (int c = 0; c < 4; ++c)
#pragma unroll
    for (int kk = 0; kk < 2; ++kk)
      bv[c][kk] = ld_cvt8(v + ((size_t)b * N_ + row0 + c * 16 + l15) * CIN_ + kk * 32 + g * 8);

#pragma unroll
  for (int hh = 0; hh < 2; ++hh) {
    const int h = w * 2 + hh;
    bf16x8 aw[4][2];
#pragma unroll
    for (int mj = 0; mj < 4; ++mj)
#pragma unroll
      for (int kk = 0; kk < 2; ++kk)
        aw[mj][kk] = ld_cvt8(wq + (size_t)(h * 64 + mj * 16 + l15) * CIN_ + kk * 32 + g * 8);
    f32x4 qb4[4], lw4[4], lb4[4];
#pragma unroll
    for (int mj = 0; mj < 4; ++mj) {
      const int base = h * 64 + mj * 16 + g * 4;
      qb4[mj] = *reinterpret_cast<const f32x4*>(qbias + base);
      lw4[mj] = *reinterpret_cast<const f32x4*>(lnqw + base);
      lb4[mj] = *reinterpret_cast<const f32x4*>(lnqb + base);
    }
    f32x4 acc[4][4];
#pragma unroll
    for (int mj = 0; mj < 4; ++mj)
#pragma unroll
      for (int c = 0; c < 4; ++c) {
        f32x4 a = z4;
        a = __builtin_amdgcn_mfma_f32_16x16x32_bf16(aw[mj][0], bv[c][0], a, 0, 0, 0);
        a = __builtin_amdgcn_mfma_f32_16x16x32_bf16(aw[mj][1], bv[c][1], a, 0, 0, 0);
        acc[mj][c] = a;
      }
#pragma unroll
    for (int c = 0; c < 4; ++c) {
      float s = 0.f, ss = 0.f;
#pragma unroll
      for (int mj = 0; mj < 4; ++mj)
#pragma unroll
        for (int r = 0; r < 4; ++r) {
          float x = acc[mj][c][r] + qb4[mj][r];
          acc[mj][c][r] = x;
          s += x; ss += x * x;
        }
      s += __shfl_xor(s, 16); ss += __shfl_xor(ss, 16);
      s += __shfl_xor(s, 32); ss += __shfl_xor(ss, 32);
      const float mu = s * (1.f / 64.f);
      const float var = ss * (1.f / 64.f) - mu * mu;
      const float rstd = rsqrtf(var + EPS_);
#pragma unroll
      for (int mj = 0; mj < 4; ++mj)
#pragma unroll
        for (int r = 0; r < 4; ++r)
          acc[mj][c][r] = (acc[mj][c][r] - mu) * rstd * lw4[mj][r] + lb4[mj][r];
    }
#pragma unroll
    for (int mj = 0; mj < 4; ++mj)
#pragma unroll
      for (int c = 0; c < 4; ++c) {
        bf16x4 p;
#pragma unroll
        for (int r = 0; r < 4; ++r) p[r] = (__bf16)acc[mj][c][r];
        *reinterpret_cast<bf16x4*>(&Qt[c * 16 + l15][h * 64 + mj * 16 + g * 4]) = p;
      }
  }

  // ---- phase 2: Mt A-frags (precomputed bf16 hi+lo planes), E-slice w*16 ----
  bf16x8 mhi[16], mlo[16];
  {
    const size_t rb = ((size_t)b * 64 + w * 16 + l15) * HD_ + g * 8;
#pragma unroll
    for (int kk = 0; kk < 16; ++kk) {
      mhi[kk] = *reinterpret_cast<const bf16x8*>(MtH + rb + kk * 32);
      mlo[kk] = *reinterpret_cast<const bf16x8*>(MtL + rb + kk * 32);
    }
  }
  __syncthreads();

  // ---- final GEMM: out^T[E-slice, n] = (Mhi+Mlo) @ Qt^T, Qt streamed ----
  f32x4 acc2[4];
#pragma unroll
  for (int et = 0; et < 4; ++et) acc2[et] = z4;
  for (int kk = 0; kk < 16; ++kk) {
#pragma unroll
    for (int et = 0; et < 4; ++et) {
      bf16x8 bq = *reinterpret_cast<const bf16x8*>(&Qt[et * 16 + l15][kk * 32 + g * 8]);
      acc2[et] = __builtin_amdgcn_mfma_f32_16x16x32_bf16(mhi[kk], bq, acc2[et], 0, 0, 0);
      acc2[et] = __builtin_amdgcn_mfma_f32_16x16x32_bf16(mlo[kk], bq, acc2[et], 0, 0, 0);
    }
  }
  // D[m=E_local=g*4+r][ncol=n_local=l15]; store f32x4 along E
  f32x4 ob4;
#pragma unroll
  for (int r = 0; r < 4; ++r) ob4[r] = obias[w * 16 + g * 4 + r] * (1.0f / N_);
#pragma unroll
  for (int et = 0; et < 4; ++et) {
    f32x4 res = acc2[et] + ob4;
    *reinterpret_cast<f32x4*>(
        out + ((size_t)b * N_ + row0 + et * 16 + l15) * 64 + w * 16 + g * 4) = res;
  }
}

// ---------------- launch ----------------
extern "C" void kernel_launch(void* const* d_in, const int* in_sizes, int n_in,
                              void* d_out, int out_size, void* d_ws, size_t ws_size,
                              hipStream_t stream) {
  const float* v     = (const float*)d_in[0];
  const float* Wq_w  = (const float*)d_in[1];
  const float* Wq_b  = (const float*)d_in[2];
  const float* Wk_w  = (const float*)d_in[3];
  const float* Wk_b  = (const float*)d_in[4];
  const float* Wv_w  = (const float*)d_in[5];
  const float* Wv_b  = (const float*)d_in[6];
  const float* lnq_w = (const float*)d_in[7];
  const float* lnq_b = (const float*)d_in[8];
  const float* lnk_w = (const float*)d_in[9];
  const float* lnk_b = (const float*)d_in[10];
  const float* o_w   = (const float*)d_in[11];
  const float* o_b   = (const float*)d_in[12];
  float* out = (float*)d_out;
  char* ws = (char*)d_ws;
  if (ws_size < WS_NEED) return;

  __bf16* MtH  = (__bf16*)(ws + OFF_MTH);
  __bf16* MtL  = (__bf16*)(ws + OFF_MTL);
  float*  KVg  = (float*)(ws + OFF_KVG);
  float*  part = (float*)(ws + OFF_PART);

  k1_kv<<<dim3(NCH_, H_, B_), 256, 0, stream>>>(v, Wk_w, Wv_w, Wk_b, Wv_b, lnk_w, lnk_b, part);
  k2a_reduce<<<dim3(16, H_, B_), 256, 0, stream>>>(part, KVg);
  k2b_mt<<<dim3(4, H_, B_), 256, 0, stream>>>(KVg, o_w, MtH, MtL);
  k3_out<<<dim3(N_ / 64, B_), 256, 0, stream>>>(v, Wq_w, Wq_b, lnq_w, lnq_b, MtH, MtL, o_b, out);
}